// Round 1
// baseline (92.282 us; speedup 1.0000x reference)
//
#include <hip/hip_runtime.h>
#include <cstddef>

// Problem constants (from reference setup_inputs):
// B=8, Tx=256, Ty=256, E=256, D=256
#define NB 8
#define TX 256
#define TY 256
#define NE 256

// tanh(x) = 1 - 2/(1+exp(2x)); exp via v_exp_f32, rcp via v_rcp_f32.
// Saturates correctly at +-1 for large |x| (exp->inf -> rcp->0; exp->0 -> r=1/1... )
__device__ __forceinline__ float fast_tanh(float x) {
    float p = __expf(x + x);                      // v_mul + v_exp_f32
    float r = __builtin_amdgcn_rcpf(p + 1.0f);    // v_add + v_rcp_f32
    return __builtin_fmaf(-2.0f, r, 1.0f);        // v_fma
}

// Kernel 1: compute WsT[b][e][x] = sum_k enc[b][x][k] * Wa[k][e]   (transposed store)
//           and     Uh[b][y][e]  = sum_k dec[b][y][k] * Ua[k][e]
// Grid: 512 blocks of (64,4). Blocks 0..255 -> Ws (b = blk/32, 8 x-rows each),
// blocks 256..511 -> Uh.
__global__ __launch_bounds__(256) void prep_kernel(
    const float* __restrict__ enc, const float* __restrict__ dec,
    const float* __restrict__ Wa, const float* __restrict__ Ua,
    float* __restrict__ WsT, float* __restrict__ Uh)
{
    const int tx = threadIdx.x;           // 0..63
    const int ty = threadIdx.y;           // 0..3
    int blk = blockIdx.x;
    const bool isU = blk >= 256;
    if (isU) blk -= 256;
    const int b  = blk >> 5;              // 0..7
    const int r0 = (blk & 31) * 8;        // row-tile start (x or y), 8 rows

    const float* in = isU ? dec : enc;
    const float* M  = isU ? Ua  : Wa;

    __shared__ float rowsL[8][NE];
    const float* src = in + ((size_t)b * 256 + r0) * NE;
    const int tid = ty * 64 + tx;
    #pragma unroll
    for (int i = tid; i < 8 * NE; i += 256) {
        rowsL[i >> 8][i & 255] = src[i];
    }
    __syncthreads();

    const int e0 = tx * 4;
    float4 acc0 = make_float4(0.f, 0.f, 0.f, 0.f);  // row r0+ty
    float4 acc1 = make_float4(0.f, 0.f, 0.f, 0.f);  // row r0+ty+4

    #pragma unroll 4
    for (int k = 0; k < NE; ++k) {
        const float4 w = *reinterpret_cast<const float4*>(M + (size_t)k * NE + e0);
        const float a = rowsL[ty][k];
        const float c = rowsL[ty + 4][k];
        acc0.x = __builtin_fmaf(a, w.x, acc0.x);
        acc0.y = __builtin_fmaf(a, w.y, acc0.y);
        acc0.z = __builtin_fmaf(a, w.z, acc0.z);
        acc0.w = __builtin_fmaf(a, w.w, acc0.w);
        acc1.x = __builtin_fmaf(c, w.x, acc1.x);
        acc1.y = __builtin_fmaf(c, w.y, acc1.y);
        acc1.z = __builtin_fmaf(c, w.z, acc1.z);
        acc1.w = __builtin_fmaf(c, w.w, acc1.w);
    }

    if (!isU) {
        // WsT[b][e][x]: thread's values are (e = e0+j, x = r0+ty and r0+ty+4)
        float a0[4] = {acc0.x, acc0.y, acc0.z, acc0.w};
        float a1[4] = {acc1.x, acc1.y, acc1.z, acc1.w};
        float* base = WsT + (size_t)b * NE * TX + r0 + ty;
        #pragma unroll
        for (int j = 0; j < 4; ++j) {
            base[(size_t)(e0 + j) * TX]     = a0[j];
            base[(size_t)(e0 + j) * TX + 4] = a1[j];
        }
    } else {
        // Uh[b][y][e]: fully coalesced float4 stores
        *reinterpret_cast<float4*>(Uh + ((size_t)b * TY + r0 + ty) * NE + e0)     = acc0;
        *reinterpret_cast<float4*>(Uh + ((size_t)b * TY + r0 + ty + 4) * NE + e0) = acc1;
    }
}

// Kernel 2: per (b, y-tile of 4): scores -> softmax -> context.
// Block (64,4): wave w handles y = y0+w fully (softmax reduce = 64-lane shfl).
// Thread (tx,ty): x-range [4tx,4tx+4) in score phase; e-range [4tx,4tx+4) in context.
__global__ __launch_bounds__(256) void attn_kernel(
    const float* __restrict__ enc, const float* __restrict__ WsT,
    const float* __restrict__ Uh, const float* __restrict__ Va,
    float* __restrict__ c_out, float* __restrict__ e_out)
{
    const int tx = threadIdx.x;            // 0..63
    const int ty = threadIdx.y;            // 0..3
    const int b  = blockIdx.x >> 6;        // 0..7
    const int y0 = (blockIdx.x & 63) * 4;  // y-tile start
    const int y  = y0 + ty;

    __shared__ float uhL[4][NE];
    __shared__ float vL[NE];
    __shared__ float pL[4][TX];

    const int tid = ty * 64 + tx;
    {
        const float* src = Uh + ((size_t)b * TY + y0) * NE;
        #pragma unroll
        for (int i = tid; i < 4 * NE; i += 256) uhL[i >> 8][i & 255] = src[i];
        if (tid < NE) vL[tid] = Va[tid];
    }
    __syncthreads();

    // ---- Phase B: scores over x ----
    const int x0 = tx * 4;
    float s0 = 0.f, s1 = 0.f, s2 = 0.f, s3 = 0.f;
    const float* wp = WsT + (size_t)b * NE * TX + x0;
    #pragma unroll 4
    for (int e = 0; e < NE; ++e) {
        const float4 w = *reinterpret_cast<const float4*>(wp + (size_t)e * TX);
        const float uh = uhL[ty][e];
        const float v  = vL[e];
        s0 = __builtin_fmaf(fast_tanh(w.x + uh), v, s0);
        s1 = __builtin_fmaf(fast_tanh(w.y + uh), v, s1);
        s2 = __builtin_fmaf(fast_tanh(w.z + uh), v, s2);
        s3 = __builtin_fmaf(fast_tanh(w.w + uh), v, s3);
    }

    // ---- Softmax over x (within one 64-lane wave; each wave = one y) ----
    float m = fmaxf(fmaxf(s0, s1), fmaxf(s2, s3));
    #pragma unroll
    for (int off = 32; off; off >>= 1) m = fmaxf(m, __shfl_xor(m, off));
    float p0 = __expf(s0 - m);
    float p1 = __expf(s1 - m);
    float p2 = __expf(s2 - m);
    float p3 = __expf(s3 - m);
    float sum = p0 + p1 + p2 + p3;
    #pragma unroll
    for (int off = 32; off; off >>= 1) sum += __shfl_xor(sum, off);
    const float inv = __builtin_amdgcn_rcpf(sum);
    const float4 p = make_float4(p0 * inv, p1 * inv, p2 * inv, p3 * inv);

    *reinterpret_cast<float4*>(&pL[ty][x0]) = p;
    *reinterpret_cast<float4*>(e_out + ((size_t)b * TY + y) * TX + x0) = p;
    __syncthreads();

    // ---- Phase D: context c[b][y][e] = sum_x p[x] * enc[b][x][e] ----
    const int e0 = tx * 4;
    float4 cacc = make_float4(0.f, 0.f, 0.f, 0.f);
    const float* ep = enc + (size_t)b * TX * NE + e0;
    #pragma unroll 4
    for (int x = 0; x < TX; ++x) {
        const float4 ev = *reinterpret_cast<const float4*>(ep + (size_t)x * NE);
        const float pv = pL[ty][x];
        cacc.x = __builtin_fmaf(pv, ev.x, cacc.x);
        cacc.y = __builtin_fmaf(pv, ev.y, cacc.y);
        cacc.z = __builtin_fmaf(pv, ev.z, cacc.z);
        cacc.w = __builtin_fmaf(pv, ev.w, cacc.w);
    }
    *reinterpret_cast<float4*>(c_out + ((size_t)b * TY + y) * NE + e0) = cacc;
}

extern "C" void kernel_launch(void* const* d_in, const int* in_sizes, int n_in,
                              void* d_out, int out_size, void* d_ws, size_t ws_size,
                              hipStream_t stream) {
    const float* enc = (const float*)d_in[0];   // [B,Tx,E]
    const float* dec = (const float*)d_in[1];   // [B,Ty,D]
    const float* Wa  = (const float*)d_in[2];   // [E,E]
    const float* Ua  = (const float*)d_in[3];   // [D,E]
    const float* Va  = (const float*)d_in[4];   // [E,1]

    float* c_out = (float*)d_out;                               // [B,Ty,E]
    float* e_out = (float*)d_out + (size_t)NB * TY * NE;        // [B,Ty,Tx]

    float* WsT = (float*)d_ws;                                  // [B][E][Tx]  2 MB
    float* Uh  = (float*)d_ws + (size_t)NB * NE * TX;           // [B][Ty][E]  2 MB

    dim3 blk(64, 4);
    prep_kernel<<<512, blk, 0, stream>>>(enc, dec, Wa, Ua, WsT, Uh);
    attn_kernel<<<512, blk, 0, stream>>>(enc, WsT, Uh, Va, c_out, e_out);
}

// Round 2
// 82.105 us; speedup vs baseline: 1.1239x; 1.1239x over previous
//
#include <hip/hip_runtime.h>
#include <cstddef>

// Problem constants: B=8, Tx=Ty=E=D=256
#define NB 8
#define TX 256
#define TY 256
#define NE 256

// 2*log2(e): pre-scale factor so score uses native exp2.
// tanh(w+uh) = 1 - 2*rcp(1 + exp2(CSC*(w+uh)))
// softmax(sum_e v*tanh(...)) == softmax(-2 * sum_e v*rcp(1+exp2(w'+uh')))
// (the constant sum_e v cancels in softmax)
#define CSC 2.8853900817779268f

// Kernel 1: WsT[b][e][x] = CSC * sum_k enc[b][x][k]*Wa[k][e]  (transposed, pre-scaled)
//           Uh [b][y][e] = CSC * sum_k dec[b][y][k]*Ua[k][e]  (pre-scaled)
// Grid: 1024 blocks of (64,4). blk<512 -> Ws (4 x-rows), else Uh (4 y-rows).
__global__ __launch_bounds__(256) void prep_kernel(
    const float* __restrict__ enc, const float* __restrict__ dec,
    const float* __restrict__ Wa, const float* __restrict__ Ua,
    float* __restrict__ WsT, float* __restrict__ Uh)
{
    const int tx = threadIdx.x;           // 0..63
    const int ty = threadIdx.y;           // 0..3
    int blk = blockIdx.x;
    const bool isU = blk >= 512;
    if (isU) blk -= 512;
    const int b  = blk >> 6;              // 0..7
    const int r0 = (blk & 63) * 4;        // row-tile start, 4 rows

    const float* in = isU ? dec : enc;
    const float* M  = isU ? Ua  : Wa;

    __shared__ float rowsL[4][NE];
    const float* src = in + ((size_t)b * 256 + r0) * NE;
    const int tid = ty * 64 + tx;
    #pragma unroll
    for (int i = tid; i < 4 * NE; i += 256) rowsL[i >> 8][i & 255] = src[i];
    __syncthreads();

    const int e0 = tx * 4;
    float4 acc = make_float4(0.f, 0.f, 0.f, 0.f);   // row r0+ty, cols e0..e0+3

    #pragma unroll 4
    for (int k = 0; k < NE; ++k) {
        const float4 w = *reinterpret_cast<const float4*>(M + (size_t)k * NE + e0);
        const float a = rowsL[ty][k];
        acc.x = __builtin_fmaf(a, w.x, acc.x);
        acc.y = __builtin_fmaf(a, w.y, acc.y);
        acc.z = __builtin_fmaf(a, w.z, acc.z);
        acc.w = __builtin_fmaf(a, w.w, acc.w);
    }
    acc.x *= CSC; acc.y *= CSC; acc.z *= CSC; acc.w *= CSC;

    if (!isU) {
        const float vals[4] = {acc.x, acc.y, acc.z, acc.w};
        float* base = WsT + (size_t)b * NE * TX + (r0 + ty);
        #pragma unroll
        for (int j = 0; j < 4; ++j) base[(size_t)(e0 + j) * TX] = vals[j];
    } else {
        *reinterpret_cast<float4*>(Uh + ((size_t)b * TY + r0 + ty) * NE + e0) = acc;
    }
}

// Kernel 2: scores -> softmax -> context.
// Grid: 1024 blocks (b = blk>>7, y-pair = (blk&127)*2), block (64,8) = 8 waves.
// Wave w: yl = w>>2 (which of the 2 y's), xq = w&3 (x quarter). 1 x per lane.
__global__ __launch_bounds__(512, 8) void attn_kernel(
    const float* __restrict__ enc, const float* __restrict__ WsT,
    const float* __restrict__ Uh, const float* __restrict__ Va,
    float* __restrict__ c_out, float* __restrict__ e_out)
{
    const int tx = threadIdx.x;            // 0..63
    const int w  = threadIdx.y;            // 0..7
    const int yl = w >> 2;                 // 0..1
    const int xq = w & 3;                  // 0..3
    const int b  = blockIdx.x >> 7;        // 0..7
    const int y0 = (blockIdx.x & 127) * 2;
    const int y  = y0 + yl;

    __shared__ float uhL[2][NE];
    __shared__ float vL[NE];
    __shared__ float mredL[2][4];
    __shared__ float sredL[2][4];
    __shared__ float4 ctxL[2][4][64];      // 8 KB

    const int tid = w * 64 + tx;
    {
        const float* uhsrc = Uh + ((size_t)b * TY + y0) * NE;   // 512 floats
        #pragma unroll
        for (int i = tid; i < 768; i += 512) {
            if (i < 512) uhL[i >> 8][i & 255] = uhsrc[i];
            else         vL[i - 512] = Va[i - 512];
        }
    }
    __syncthreads();

    // ---- scores: acc = sum_e v[e] * rcp(1 + exp2(w'[e][x] + uh'[y][e])) ----
    const int x = xq * 64 + tx;
    const float* wp = WsT + (size_t)b * NE * TX + x;
    float acc = 0.f;
    #pragma unroll 2
    for (int e = 0; e < NE; e += 4) {
        const float4 uh4 = *reinterpret_cast<const float4*>(&uhL[yl][e]);
        const float4 v4  = *reinterpret_cast<const float4*>(&vL[e]);
        const float w0 = wp[(size_t)(e + 0) * TX];
        const float w1 = wp[(size_t)(e + 1) * TX];
        const float w2 = wp[(size_t)(e + 2) * TX];
        const float w3 = wp[(size_t)(e + 3) * TX];
        float r0 = __builtin_amdgcn_rcpf(1.f + __builtin_amdgcn_exp2f(w0 + uh4.x));
        float r1 = __builtin_amdgcn_rcpf(1.f + __builtin_amdgcn_exp2f(w1 + uh4.y));
        float r2 = __builtin_amdgcn_rcpf(1.f + __builtin_amdgcn_exp2f(w2 + uh4.z));
        float r3 = __builtin_amdgcn_rcpf(1.f + __builtin_amdgcn_exp2f(w3 + uh4.w));
        acc = __builtin_fmaf(v4.x, r0, acc);
        acc = __builtin_fmaf(v4.y, r1, acc);
        acc = __builtin_fmaf(v4.z, r2, acc);
        acc = __builtin_fmaf(v4.w, r3, acc);
    }
    const float s = -2.f * acc;

    // ---- softmax over x: wave reduce + 4-partial cross-wave combine ----
    float m = s;
    #pragma unroll
    for (int off = 32; off; off >>= 1) m = fmaxf(m, __shfl_xor(m, off));
    if (tx == 0) mredL[yl][xq] = m;
    __syncthreads();
    m = fmaxf(fmaxf(mredL[yl][0], mredL[yl][1]), fmaxf(mredL[yl][2], mredL[yl][3]));

    float p = __expf(s - m);
    float sum = p;
    #pragma unroll
    for (int off = 32; off; off >>= 1) sum += __shfl_xor(sum, off);
    if (tx == 0) sredL[yl][xq] = sum;
    __syncthreads();
    const float tot = (sredL[yl][0] + sredL[yl][1]) + (sredL[yl][2] + sredL[yl][3]);
    p *= __builtin_amdgcn_rcpf(tot);

    e_out[((size_t)b * TY + y) * TX + x] = p;

    // ---- context partial: this wave covers x in [xq*64, xq*64+64) ----
    const int e0 = tx * 4;
    const float* ep = enc + (size_t)b * TX * NE + e0;
    float4 cacc = make_float4(0.f, 0.f, 0.f, 0.f);
    #pragma unroll 4
    for (int i = 0; i < 64; ++i) {
        const float pv = __shfl(p, i);
        const float4 ev = *reinterpret_cast<const float4*>(ep + (size_t)(xq * 64 + i) * NE);
        cacc.x = __builtin_fmaf(pv, ev.x, cacc.x);
        cacc.y = __builtin_fmaf(pv, ev.y, cacc.y);
        cacc.z = __builtin_fmaf(pv, ev.z, cacc.z);
        cacc.w = __builtin_fmaf(pv, ev.w, cacc.w);
    }
    ctxL[yl][xq][tx] = cacc;
    __syncthreads();

    if (xq == 0) {
        const float4 c0 = ctxL[yl][0][tx];
        const float4 c1 = ctxL[yl][1][tx];
        const float4 c2 = ctxL[yl][2][tx];
        const float4 c3 = ctxL[yl][3][tx];
        float4 cs;
        cs.x = (c0.x + c1.x) + (c2.x + c3.x);
        cs.y = (c0.y + c1.y) + (c2.y + c3.y);
        cs.z = (c0.z + c1.z) + (c2.z + c3.z);
        cs.w = (c0.w + c1.w) + (c2.w + c3.w);
        *reinterpret_cast<float4*>(c_out + ((size_t)b * TY + y) * NE + e0) = cs;
    }
}

extern "C" void kernel_launch(void* const* d_in, const int* in_sizes, int n_in,
                              void* d_out, int out_size, void* d_ws, size_t ws_size,
                              hipStream_t stream) {
    const float* enc = (const float*)d_in[0];   // [B,Tx,E]
    const float* dec = (const float*)d_in[1];   // [B,Ty,D]
    const float* Wa  = (const float*)d_in[2];   // [E,E]
    const float* Ua  = (const float*)d_in[3];   // [D,E]
    const float* Va  = (const float*)d_in[4];   // [E,1]

    float* c_out = (float*)d_out;                               // [B,Ty,E]
    float* e_out = (float*)d_out + (size_t)NB * TY * NE;        // [B,Ty,Tx]

    float* WsT = (float*)d_ws;                                  // [B][E][Tx]
    float* Uh  = (float*)d_ws + (size_t)NB * NE * TX;           // [B][Ty][E]

    prep_kernel<<<1024, dim3(64, 4), 0, stream>>>(enc, dec, Wa, Ua, WsT, Uh);
    attn_kernel<<<1024, dim3(64, 8), 0, stream>>>(enc, WsT, Uh, Va, c_out, e_out);
}

// Round 3
// 76.528 us; speedup vs baseline: 1.2059x; 1.0729x over previous
//
#include <hip/hip_runtime.h>
#include <cstddef>
#include <stdint.h>

// Problem constants: B=8, Tx=Ty=E=D=256
#define NB 8
#define TX 256
#define TY 256
#define NE 256

// 2*log2(e): tanh(t) = 1 - 2*rcp(1+exp2(CSC*t)); the constant 1-term cancels in
// softmax, so score s = -2 * sum_e v[e]*rcp(1+exp2(ws'[e][x]+uh'[y][e]))
#define CSC 2.8853900817779268f

__device__ __forceinline__ void gload_lds16(const float* g, float* l) {
    __builtin_amdgcn_global_load_lds(
        (const __attribute__((address_space(1))) void*)g,
        (__attribute__((address_space(3))) void*)l,
        16, 0, 0);
}

// ---------------- prep: WsT[b][e][x] and Uh[b][y][e], both pre-scaled by CSC ----
// Grid 512 x (64,8). blk<256 -> Ws tiles (8 x-rows), blk>=256 -> Uh tiles (8 y-rows).
__global__ __launch_bounds__(512) void prep_kernel(
    const float* __restrict__ enc, const float* __restrict__ dec,
    const float* __restrict__ Wa, const float* __restrict__ Ua,
    float* __restrict__ WsT, float* __restrict__ Uh)
{
    const int tx = threadIdx.x;           // 0..63
    const int ty = threadIdx.y;           // 0..7
    const int tid = ty * 64 + tx;
    int blk = blockIdx.x;
    const bool isU = blk >= 256;
    if (isU) blk -= 256;
    const int b  = blk >> 5;              // 0..7
    const int r0 = (blk & 31) * 8;        // 8 rows per block

    __shared__ float rowsL[8 * NE];       // 8 KB input rows
    __shared__ float tL[8][260];          // transpose buffer (Ws only), padded

    const float* src = (isU ? dec : enc) + ((size_t)b * 256 + r0) * NE;
    ((float4*)rowsL)[tid] = ((const float4*)src)[tid];   // 2048 floats
    __syncthreads();

    const float* M = isU ? Ua : Wa;
    const int e0 = tx * 4;
    float4 acc = make_float4(0.f, 0.f, 0.f, 0.f);
    const float* rrow = rowsL + ty * NE;
    #pragma unroll 4
    for (int k = 0; k < NE; ++k) {
        const float4 mw = *(const float4*)(M + (size_t)k * NE + e0);
        const float a = rrow[k];
        acc.x = __builtin_fmaf(a, mw.x, acc.x);
        acc.y = __builtin_fmaf(a, mw.y, acc.y);
        acc.z = __builtin_fmaf(a, mw.z, acc.z);
        acc.w = __builtin_fmaf(a, mw.w, acc.w);
    }
    acc.x *= CSC; acc.y *= CSC; acc.z *= CSC; acc.w *= CSC;

    if (isU) {
        *(float4*)(Uh + ((size_t)b * TY + r0 + ty) * NE + e0) = acc;
    } else {
        *(float4*)&tL[ty][e0] = acc;
        __syncthreads();
        // coalesced transposed store: thread -> (e = tid>>1, 4 x's)
        const int e    = tid >> 1;
        const int half = (tid & 1) * 4;
        float4 o;
        o.x = tL[half + 0][e];
        o.y = tL[half + 1][e];
        o.z = tL[half + 2][e];
        o.w = tL[half + 3][e];
        *(float4*)(WsT + (size_t)b * NE * TX + (size_t)e * TX + r0 + half) = o;
    }
}

// ---------------- attn: scores -> softmax -> context ----------------
// Grid 512 = (b, y-tile of 4). Block (64,8) = 8 waves.
// Score: wave (yl = w>>1, xh = w&1); lane covers x0 = xh*128+tx and x0+64.
// Context: wave w covers x-sub [w*4,w*4+4) of each staged 32-x chunk,
//          lane covers e = tx*4 float4, accumulating all 4 y's.
__global__ __launch_bounds__(512) void attn_kernel(
    const float* __restrict__ enc, const float* __restrict__ WsT,
    const float* __restrict__ Uh, const float* __restrict__ Va,
    float* __restrict__ c_out, float* __restrict__ e_out)
{
    const int tx = threadIdx.x;            // 0..63
    const int w  = threadIdx.y;            // 0..7
    const int tid = w * 64 + tx;
    const int yl = w >> 1;                 // 0..3
    const int xh = w & 1;                  // 0..1
    const int b  = blockIdx.x >> 6;        // 0..7
    const int y0 = (blockIdx.x & 63) * 4;

    __shared__ float  wsL[32 * 256];       // 32 KB: ws chunks / enc chunks / ctx combine
    __shared__ float2 uvL[4][NE];          // 8 KB: (uh'[y][e], v[e])
    __shared__ float  pL4[TX][4];          // 4 KB: p[x][yl]
    __shared__ float  redM[4][2];
    __shared__ float  redS[4][2];

    // stage (uh, v) pairs for the 4 y's
    #pragma unroll
    for (int i = tid; i < 4 * NE; i += 512) {
        const int yy = i >> 8;
        const int e  = i & 255;
        uvL[yy][e] = make_float2(Uh[((size_t)b * TY + y0 + yy) * NE + e], Va[e]);
    }

    // ---- score phase: 8 e-chunks of 32, staged via global_load_lds ----
    const int x0 = xh * 128 + tx;
    float a0 = 0.f, a1 = 0.f;
    const float* wsrc = WsT + (size_t)b * NE * TX;
    for (int ec = 0; ec < 8; ++ec) {
        #pragma unroll
        for (int r = 0; r < 4; ++r)
            gload_lds16(wsrc + ec * 8192 + r * 2048 + tid * 4,
                        wsL + r * 2048 + w * 256);
        __syncthreads();
        const float2* uvy = &uvL[yl][ec * 32];
        #pragma unroll 8
        for (int e = 0; e < 32; ++e) {
            const float2 uv = uvy[e];
            const float w0 = wsL[e * 256 + x0];
            const float w1 = wsL[e * 256 + x0 + 64];
            const float r0v = __builtin_amdgcn_rcpf(1.f + __builtin_amdgcn_exp2f(w0 + uv.x));
            const float r1v = __builtin_amdgcn_rcpf(1.f + __builtin_amdgcn_exp2f(w1 + uv.x));
            a0 = __builtin_fmaf(uv.y, r0v, a0);
            a1 = __builtin_fmaf(uv.y, r1v, a1);
        }
        __syncthreads();
    }

    // ---- softmax over x (wave reduce + 2-wave combine per y) ----
    const float s0 = -2.f * a0, s1 = -2.f * a1;
    float m = fmaxf(s0, s1);
    #pragma unroll
    for (int off = 32; off; off >>= 1) m = fmaxf(m, __shfl_xor(m, off));
    if (tx == 0) redM[yl][xh] = m;
    __syncthreads();
    m = fmaxf(redM[yl][0], redM[yl][1]);
    float p0 = __expf(s0 - m), p1 = __expf(s1 - m);
    float sum = p0 + p1;
    #pragma unroll
    for (int off = 32; off; off >>= 1) sum += __shfl_xor(sum, off);
    if (tx == 0) redS[yl][xh] = sum;
    __syncthreads();
    const float inv = __builtin_amdgcn_rcpf(redS[yl][0] + redS[yl][1]);
    p0 *= inv; p1 *= inv;
    const int y = y0 + yl;
    e_out[((size_t)b * TY + y) * TX + x0]      = p0;
    e_out[((size_t)b * TY + y) * TX + x0 + 64] = p1;
    pL4[x0][yl]      = p0;
    pL4[x0 + 64][yl] = p1;

    // ---- context: c[y][e] = sum_x p[y][x]*enc[b][x][e], enc staged in chunks ----
    float4 c0 = make_float4(0.f,0.f,0.f,0.f), c1 = c0, c2 = c0, c3 = c0;
    const float* esrc = enc + (size_t)b * TX * NE;
    const int e4 = tx * 4;
    for (int xc = 0; xc < 8; ++xc) {
        #pragma unroll
        for (int r = 0; r < 4; ++r)
            gload_lds16(esrc + xc * 8192 + r * 2048 + tid * 4,
                        wsL + r * 2048 + w * 256);
        __syncthreads();
        #pragma unroll
        for (int j = 0; j < 4; ++j) {
            const int xr = w * 4 + j;
            const float4 p4 = *(const float4*)&pL4[xc * 32 + xr][0];
            const float4 ev = *(const float4*)&wsL[xr * 256 + e4];
            c0.x = __builtin_fmaf(p4.x, ev.x, c0.x);
            c0.y = __builtin_fmaf(p4.x, ev.y, c0.y);
            c0.z = __builtin_fmaf(p4.x, ev.z, c0.z);
            c0.w = __builtin_fmaf(p4.x, ev.w, c0.w);
            c1.x = __builtin_fmaf(p4.y, ev.x, c1.x);
            c1.y = __builtin_fmaf(p4.y, ev.y, c1.y);
            c1.z = __builtin_fmaf(p4.y, ev.z, c1.z);
            c1.w = __builtin_fmaf(p4.y, ev.w, c1.w);
            c2.x = __builtin_fmaf(p4.z, ev.x, c2.x);
            c2.y = __builtin_fmaf(p4.z, ev.y, c2.y);
            c2.z = __builtin_fmaf(p4.z, ev.z, c2.z);
            c2.w = __builtin_fmaf(p4.z, ev.w, c2.w);
            c3.x = __builtin_fmaf(p4.w, ev.x, c3.x);
            c3.y = __builtin_fmaf(p4.w, ev.y, c3.y);
            c3.z = __builtin_fmaf(p4.w, ev.z, c3.z);
            c3.w = __builtin_fmaf(p4.w, ev.w, c3.w);
        }
        __syncthreads();
    }

    // combine the 8 per-wave partials through LDS (reuse wsL)
    float4* ctxP = (float4*)wsL;           // [8 waves][4 y][64 lanes]
    ctxP[(w * 4 + 0) * 64 + tx] = c0;
    ctxP[(w * 4 + 1) * 64 + tx] = c1;
    ctxP[(w * 4 + 2) * 64 + tx] = c2;
    ctxP[(w * 4 + 3) * 64 + tx] = c3;
    __syncthreads();
    if (w < 4) {
        float4 s = make_float4(0.f,0.f,0.f,0.f);
        #pragma unroll
        for (int ww = 0; ww < 8; ++ww) {
            const float4 t = ctxP[(ww * 4 + w) * 64 + tx];
            s.x += t.x; s.y += t.y; s.z += t.z; s.w += t.w;
        }
        *(float4*)(c_out + ((size_t)b * TY + y0 + w) * NE + e4) = s;
    }
}

extern "C" void kernel_launch(void* const* d_in, const int* in_sizes, int n_in,
                              void* d_out, int out_size, void* d_ws, size_t ws_size,
                              hipStream_t stream) {
    const float* enc = (const float*)d_in[0];   // [B,Tx,E]
    const float* dec = (const float*)d_in[1];   // [B,Ty,D]
    const float* Wa  = (const float*)d_in[2];   // [E,E]
    const float* Ua  = (const float*)d_in[3];   // [D,E]
    const float* Va  = (const float*)d_in[4];   // [E,1]

    float* c_out = (float*)d_out;                               // [B,Ty,E]
    float* e_out = (float*)d_out + (size_t)NB * TY * NE;        // [B,Ty,Tx]

    float* WsT = (float*)d_ws;                                  // [B][E][Tx]
    float* Uh  = (float*)d_ws + (size_t)NB * NE * TX;           // [B][Ty][E]

    prep_kernel<<<512, dim3(64, 8), 0, stream>>>(enc, dec, Wa, Ua, WsT, Uh);
    attn_kernel<<<512, dim3(64, 8), 0, stream>>>(enc, WsT, Uh, Va, c_out, e_out);
}